// Round 2
// baseline (136.730 us; speedup 1.0000x reference)
//
#include <hip/hip_runtime.h>
#include <stdint.h>

// FusedFP4Linear: out = gelu(x @ dequant(w_fp4)^T + bias)
// M=128, K=4096, N=16384. Weights: [N, K/2] int32, each int = one packed byte
// = two FP4 (E2M1) indices (hi = even k, lo = odd k).
// R2: register-prefetch pipeline (loads for tile k+1 issued before MFMA of
// tile k, 2x-unrolled loop) + 2x2 wave tiling (each wave 32x32 out, A-frag
// reuse across 2 B-frags) to cut LDS read traffic 20%.

#define M_DIM 128
#define K_DIM 4096
#define N_DIM 16384
#define KP    (K_DIM/2)     // ints per weight row = 2048
#define BN    64
#define BK    128           // k elements per LDS tile
#define BKI   (BK/2)        // ints per row per tile = 64
#define LDT   (BK + 8)      // padded ushort stride = 136 (2-way bank alias = free)
#define NT    512           // 8 waves
#define NK    (K_DIM / BK)  // 32 k-tiles

typedef __attribute__((ext_vector_type(8))) __bf16 bf16x8;
typedef __attribute__((ext_vector_type(4))) float  f32x4;
typedef unsigned short ushort_t;

__device__ __forceinline__ unsigned f2b_bits(float f) {
  unsigned u = __builtin_bit_cast(unsigned, f);
  u += 0x7FFFu + ((u >> 16) & 1u);   // RNE
  return u >> 16;
}

__global__ void convert_x_kernel(const float* __restrict__ x,
                                 ushort_t* __restrict__ xb) {
  int i = (blockIdx.x * blockDim.x + threadIdx.x) * 4;
  float4 v = *(const float4*)(x + i);
  ushort4 p;
  p.x = (ushort_t)f2b_bits(v.x);
  p.y = (ushort_t)f2b_bits(v.y);
  p.z = (ushort_t)f2b_bits(v.z);
  p.w = (ushort_t)f2b_bits(v.w);
  *(ushort4*)(xb + i) = p;
}

template<bool USE_XB>
__global__ __launch_bounds__(NT) void fp4gemm_kernel(
    const void* __restrict__ xsrc,        // bf16 xb (ws) or fp32 x
    const int*  __restrict__ wq,          // [N, KP] packed
    const float* __restrict__ scale,      // [N]
    const float* __restrict__ bias,       // [N]
    float* __restrict__ out) {            // [M, N]
  __shared__ ushort_t As[M_DIM][LDT];     // 34816 B
  __shared__ ushort_t Bs[BN][LDT];        // 17408 B
  __shared__ unsigned tab[256];           // byte -> (bf16(hi) | bf16(lo)<<16)

  const int t   = threadIdx.x;
  const int w   = t >> 6;        // wave 0..7
  const int l   = t & 63;
  const int l16 = l & 15;
  const int lq  = l >> 4;        // 0..3
  const int mq  = w >> 1;        // m-quad (0..3): rows mq*32..+31
  const int nh  = w & 1;         // n-half (0..1): cols nh*32..+31

  if (t < 256) {
    const float FV[16] = {0.f, 0.5f, 1.f, 1.5f, 2.f, 3.f, 4.f, 6.f,
                          0.f, -0.5f, -1.f, -1.5f, -2.f, -3.f, -4.f, -6.f};
    unsigned hi = f2b_bits(FV[(t >> 4) & 15]);   // exact in bf16
    unsigned lo = f2b_bits(FV[t & 15]);
    tab[t] = hi | (lo << 16);
  }

  const int n0   = blockIdx.x * BN;
  const int brow = t >> 3;          // 0..63  (B staging row)
  const int bic  = (t & 7) * 8;     // int col 0..56 (8 ints per thread)

  f32x4 acc[2][2] = {{f32x4{0,0,0,0}, f32x4{0,0,0,0}},
                     {f32x4{0,0,0,0}, f32x4{0,0,0,0}}};

#define LOADA(dst, kt_) do { \
  _Pragma("unroll") \
  for (int i_ = 0; i_ < 4; ++i_) { \
    int c_ = i_ * NT + t; int row_ = c_ >> 4, cc_ = c_ & 15; \
    size_t off_ = (size_t)row_ * K_DIM + (kt_) * BK + cc_ * 8; \
    if constexpr (USE_XB) { \
      dst[i_] = *(const uint4*)((const ushort_t*)xsrc + off_); \
    } else { \
      const float* xf_ = (const float*)xsrc + off_; \
      float4 v0_ = *(const float4*)(xf_); \
      float4 v1_ = *(const float4*)(xf_ + 4); \
      dst[i_] = make_uint4(f2b_bits(v0_.x) | (f2b_bits(v0_.y) << 16), \
                           f2b_bits(v0_.z) | (f2b_bits(v0_.w) << 16), \
                           f2b_bits(v1_.x) | (f2b_bits(v1_.y) << 16), \
                           f2b_bits(v1_.z) | (f2b_bits(v1_.w) << 16)); \
    } \
  } \
} while (0)

#define LOADB(p0_, p1_, kt_) do { \
  const int* wrow_ = wq + (size_t)(n0 + brow) * KP + (kt_) * BKI + bic; \
  p0_ = *(const int4*)(wrow_); \
  p1_ = *(const int4*)(wrow_ + 4); \
} while (0)

#define WRITEA(src) do { \
  _Pragma("unroll") \
  for (int i_ = 0; i_ < 4; ++i_) { \
    int c_ = i_ * NT + t; int row_ = c_ >> 4, cc_ = c_ & 15; \
    *(uint4*)&As[row_][cc_ * 8] = src[i_]; \
  } \
} while (0)

#define WRITEB(p0_, p1_) do { \
  unsigned u0 = tab[p0_.x & 255], u1 = tab[p0_.y & 255]; \
  unsigned u2 = tab[p0_.z & 255], u3 = tab[p0_.w & 255]; \
  unsigned u4 = tab[p1_.x & 255], u5 = tab[p1_.y & 255]; \
  unsigned u6 = tab[p1_.z & 255], u7 = tab[p1_.w & 255]; \
  *(uint4*)&Bs[brow][bic * 2]     = make_uint4(u0, u1, u2, u3); \
  *(uint4*)&Bs[brow][bic * 2 + 8] = make_uint4(u4, u5, u6, u7); \
} while (0)

#define MFMA_TILE() do { \
  _Pragma("unroll") \
  for (int ks_ = 0; ks_ < BK / 32; ++ks_) { \
    const int ko_ = ks_ * 32 + lq * 8; \
    bf16x8 a0_ = *(const bf16x8*)&As[mq * 32 + l16][ko_]; \
    bf16x8 a1_ = *(const bf16x8*)&As[mq * 32 + 16 + l16][ko_]; \
    bf16x8 b0_ = *(const bf16x8*)&Bs[nh * 32 + l16][ko_]; \
    bf16x8 b1_ = *(const bf16x8*)&Bs[nh * 32 + 16 + l16][ko_]; \
    acc[0][0] = __builtin_amdgcn_mfma_f32_16x16x32_bf16(a0_, b0_, acc[0][0], 0, 0, 0); \
    acc[0][1] = __builtin_amdgcn_mfma_f32_16x16x32_bf16(a0_, b1_, acc[0][1], 0, 0, 0); \
    acc[1][0] = __builtin_amdgcn_mfma_f32_16x16x32_bf16(a1_, b0_, acc[1][0], 0, 0, 0); \
    acc[1][1] = __builtin_amdgcn_mfma_f32_16x16x32_bf16(a1_, b1_, acc[1][1], 0, 0, 0); \
  } \
} while (0)

  uint4 aS0[4], aS1[4];
  int4 p00, p01, p10, p11;

  LOADA(aS0, 0);
  LOADB(p00, p01, 0);

  for (int kt = 0; kt < NK; kt += 2) {
    __syncthreads();                 // prev tile consumed (iter0: tab ready)
    WRITEA(aS0);
    WRITEB(p00, p01);
    __syncthreads();
    LOADA(aS1, kt + 1);              // prefetch next tile (NK even => valid)
    LOADB(p10, p11, kt + 1);
    MFMA_TILE();                     // tile kt; loads in flight

    __syncthreads();
    WRITEA(aS1);
    WRITEB(p10, p11);
    __syncthreads();
    {
      int kn = (kt + 2 < NK) ? (kt + 2) : 0;   // clamp: dummy valid load
      LOADA(aS0, kn);
      LOADB(p00, p01, kn);
    }
    MFMA_TILE();                     // tile kt+1
  }

  // ---- epilogue: scale, bias, exact GELU, store ----
  const int ng = n0 + nh * 32 + l16;
#pragma unroll
  for (int c = 0; c < 2; ++c) {
    const int ngc = ng + c * 16;
    const float s  = scale[ngc];
    const float bb = bias[ngc];
#pragma unroll
    for (int r = 0; r < 2; ++r) {
#pragma unroll
      for (int j = 0; j < 4; ++j) {
        int m = mq * 32 + r * 16 + lq * 4 + j;
        float y = acc[r][c][j] * s + bb;
        float g = 0.5f * y * (1.0f + erff(y * 0.70710678118654752f));
        out[(size_t)m * N_DIM + ngc] = g;
      }
    }
  }
#undef LOADA
#undef LOADB
#undef WRITEA
#undef WRITEB
#undef MFMA_TILE
}

extern "C" void kernel_launch(void* const* d_in, const int* in_sizes, int n_in,
                              void* d_out, int out_size, void* d_ws, size_t ws_size,
                              hipStream_t stream) {
  const float* x     = (const float*)d_in[0];
  const int*   wq    = (const int*)d_in[1];
  const float* scale = (const float*)d_in[2];
  const float* bias  = (const float*)d_in[3];
  float* out = (float*)d_out;

  const size_t xb_bytes = (size_t)M_DIM * K_DIM * sizeof(ushort_t);  // 1 MB
  if (ws_size >= xb_bytes) {
    ushort_t* xb = (ushort_t*)d_ws;
    convert_x_kernel<<<(M_DIM * K_DIM) / (256 * 4), 256, 0, stream>>>(x, xb);
    fp4gemm_kernel<true><<<N_DIM / BN, NT, 0, stream>>>(xb, wq, scale, bias, out);
  } else {
    fp4gemm_kernel<false><<<N_DIM / BN, NT, 0, stream>>>(x, wq, scale, bias, out);
  }
}

// Round 3
// 66.766 us; speedup vs baseline: 2.0479x; 2.0479x over previous
//
#include <hip/hip_runtime.h>
#include <stdint.h>

// FusedFP4Linear: out = gelu(x @ dequant(w_fp4)^T + bias)
// M=128, K=4096, N=16384. Weights [N, K/2] int32, low byte = two FP4 nibbles
// (hi nibble = even k, lo nibble = odd k).
// R3: BN=32 / grid=512 (2 blocks/CU), global_load_lds(16B) double-buffered
// staging for A(bf16) and B(packed), one barrier per K-tile, XOR-swizzled
// LDS (pre-swizzled global source, swizzled ds_read_b128), v_perm-based
// in-register FP4->bf16 decode in the compute phase.

#define M_DIM 128
#define K_DIM 4096
#define N_DIM 16384
#define KP    (K_DIM/2)        // 2048 ints per weight row
#define BN    32
#define BK    64
#define NK    (K_DIM/BK)       // 64 k-tiles
#define NT    256              // 4 waves
#define NBLK  (N_DIM/BN)       // 512 blocks

#define A_BYTES (M_DIM*BK*2)   // 16384 (128 rows x 128B)
#define B_BYTES (BN*(BK/2)*4)  // 4096  (32 rows x 128B packed)
#define AOFF(b) ((b)*A_BYTES)
#define BOFF(b) (2*A_BYTES + (b)*B_BYTES)
#define LDS_SZ  (2*A_BYTES + 2*B_BYTES)   // 40960

typedef __attribute__((ext_vector_type(8))) __bf16 bf16x8;
typedef __attribute__((ext_vector_type(4))) float  f32x4;
typedef unsigned short ushort_t;

__device__ __forceinline__ unsigned f2b_bits(float f) {
  unsigned u = __builtin_bit_cast(unsigned, f);
  u += 0x7FFFu + ((u >> 16) & 1u);   // RNE
  return u >> 16;
}

__global__ void convert_x_kernel(const float* __restrict__ x,
                                 ushort_t* __restrict__ xb) {
  int i = (blockIdx.x * blockDim.x + threadIdx.x) * 4;
  float4 v = *(const float4*)(x + i);
  ushort4 p;
  p.x = (ushort_t)f2b_bits(v.x);
  p.y = (ushort_t)f2b_bits(v.y);
  p.z = (ushort_t)f2b_bits(v.z);
  p.w = (ushort_t)f2b_bits(v.w);
  *(ushort4*)(xb + i) = p;
}

__device__ __forceinline__ void gl16(const void* g, void* l) {
  __builtin_amdgcn_global_load_lds(
      (const __attribute__((address_space(1))) void*)g,
      (__attribute__((address_space(3))) void*)l, 16, 0, 0);
}

// 4 packed ints (low bytes only) -> 8 bf16 (k-order: byte0.hi, byte0.lo, ...)
__device__ __forceinline__ bf16x8 decode8(uint4 p) {
  unsigned u01 = __builtin_amdgcn_perm(p.y, p.x, 0x04000400u);  // [x0,y0,x0,y0]
  unsigned u23 = __builtin_amdgcn_perm(p.w, p.z, 0x04000400u);  // [z0,w0,z0,w0]
  unsigned q   = __builtin_amdgcn_perm(u23, u01, 0x05040100u);  // [x0,y0,z0,w0]
  unsigned e  = (q >> 4) & 0x0F0F0F0Fu;    // even-k nibbles
  unsigned o  = q & 0x0F0F0F0Fu;           // odd-k nibbles
  unsigned em = e & 0x07070707u, om = o & 0x07070707u;
  // magnitude byte LUTs (n=0..7): lo=[0,0,0x80,0xC0,0,0x40,0x80,0xC0]
  //                               hi=[0,0x3F,0x3F,0x3F,0x40,0x40,0x40,0x40]
  unsigned elo = __builtin_amdgcn_perm(0xC0804000u, 0xC0800000u, em);
  unsigned ehi = __builtin_amdgcn_perm(0x40404040u, 0x3F3F3F00u, em);
  unsigned olo = __builtin_amdgcn_perm(0xC0804000u, 0xC0800000u, om);
  unsigned ohi = __builtin_amdgcn_perm(0x40404040u, 0x3F3F3F00u, om);
  ehi |= (e & 0x08080808u) << 4;           // sign -> bit7 of high byte
  ohi |= (o & 0x08080808u) << 4;
  unsigned t0 = __builtin_amdgcn_perm(ehi, elo, 0x05010400u);   // [el0,eh0,el1,eh1]
  unsigned t1 = __builtin_amdgcn_perm(ohi, olo, 0x05010400u);
  unsigned t2 = __builtin_amdgcn_perm(ehi, elo, 0x07030602u);   // [el2,eh2,el3,eh3]
  unsigned t3 = __builtin_amdgcn_perm(ohi, olo, 0x07030602u);
  uint4 r;
  r.x = __builtin_amdgcn_perm(t1, t0, 0x05040100u);  // bf16(k0)|bf16(k1)<<16
  r.y = __builtin_amdgcn_perm(t1, t0, 0x07060302u);  // k2,k3
  r.z = __builtin_amdgcn_perm(t3, t2, 0x05040100u);  // k4,k5
  r.w = __builtin_amdgcn_perm(t3, t2, 0x07060302u);  // k6,k7
  return __builtin_bit_cast(bf16x8, r);
}

template<bool USE_XB>
__global__ __launch_bounds__(NT) void fp4gemm_kernel(
    const void* __restrict__ xsrc,        // bf16 xb (ws) or fp32 x
    const int*  __restrict__ wq,          // [N, KP]
    const float* __restrict__ scale,      // [N]
    const float* __restrict__ bias,       // [N]
    float* __restrict__ out) {            // [M, N]
  __shared__ __align__(16) uint8_t lds[LDS_SZ];

  const int t   = threadIdx.x;
  const int w   = t >> 6;                 // wave 0..3 (also m-quad)
  const int l   = t & 63;
  const int l16 = l & 15;
  const int lq  = l >> 4;

  // XCD-aware bijective swizzle (512 % 8 == 0)
  const int bid = blockIdx.x;
  const int n0  = ((bid & 7) * (NBLK / 8) + (bid >> 3)) * BN;

  // staging geometry: per global_load_lds inst, 256 thr x 16B = 4KB = 32 rows
  const int srow = w * 8 + (l >> 3);      // 0..31
  const int scb  = (l & 7) * 16;          // dest byte col (linear)
  const int scbs = scb ^ ((srow & 7) << 4);  // swizzled SOURCE byte col

  const uint8_t* xb  = (const uint8_t*)xsrc;  // bf16 rows: 8192 B
  const uint8_t* wqb = (const uint8_t*)wq;    // int rows: 8192 B

#define ISSUE(kt_, buf_) do { \
  if constexpr (USE_XB) { \
    _Pragma("unroll") \
    for (int i_ = 0; i_ < 4; ++i_) \
      gl16(xb + (size_t)(i_ * 32 + srow) * 8192 + (kt_) * 128 + scbs, \
           lds + AOFF(buf_) + i_ * 4096 + w * 1024); \
  } else { \
    _Pragma("unroll") \
    for (int i_ = 0; i_ < 4; ++i_) { \
      const float* xf_ = (const float*)xsrc + \
          (size_t)(i_ * 32 + srow) * K_DIM + (kt_) * BK + (scbs >> 1); \
      float4 v0_ = *(const float4*)(xf_); \
      float4 v1_ = *(const float4*)(xf_ + 4); \
      uint4 pk_ = make_uint4(f2b_bits(v0_.x) | (f2b_bits(v0_.y) << 16), \
                             f2b_bits(v0_.z) | (f2b_bits(v0_.w) << 16), \
                             f2b_bits(v1_.x) | (f2b_bits(v1_.y) << 16), \
                             f2b_bits(v1_.z) | (f2b_bits(v1_.w) << 16)); \
      *(uint4*)(lds + AOFF(buf_) + (i_ * 32 + srow) * 128 + scb) = pk_; \
    } \
  } \
  gl16(wqb + (size_t)(n0 + srow) * 8192 + (kt_) * 128 + scbs, \
       lds + BOFF(buf_) + w * 1024); \
} while (0)

  f32x4 acc[2][2] = {{f32x4{0,0,0,0}, f32x4{0,0,0,0}},
                     {f32x4{0,0,0,0}, f32x4{0,0,0,0}}};

  const int x7   = (l16 & 7) << 4;        // read-side swizzle (row&7 == l16&7)
  const int off0 = (lq << 4) ^ x7;
  const int ab0  = (w * 32 + l16) * 128;  // A row base (mi=0); mi=1 -> +2048
  const int bb0  = l16 * 128;             // B row base (ni=0); ni=1 -> +2048

#define COMPUTE(buf_) do { \
  const uint8_t* Ab_ = lds + AOFF(buf_); \
  const uint8_t* Bb_ = lds + BOFF(buf_); \
  _Pragma("unroll") \
  for (int ks_ = 0; ks_ < BK / 32; ++ks_) { \
    const int offk_ = off0 ^ (ks_ << 6); \
    bf16x8 a0_ = *(const bf16x8*)(Ab_ + ab0 + offk_); \
    bf16x8 a1_ = *(const bf16x8*)(Ab_ + ab0 + 2048 + offk_); \
    uint4 pb0_ = *(const uint4*)(Bb_ + bb0 + offk_); \
    uint4 pb1_ = *(const uint4*)(Bb_ + bb0 + 2048 + offk_); \
    bf16x8 b0_ = decode8(pb0_); \
    bf16x8 b1_ = decode8(pb1_); \
    acc[0][0] = __builtin_amdgcn_mfma_f32_16x16x32_bf16(a0_, b0_, acc[0][0], 0, 0, 0); \
    acc[0][1] = __builtin_amdgcn_mfma_f32_16x16x32_bf16(a0_, b1_, acc[0][1], 0, 0, 0); \
    acc[1][0] = __builtin_amdgcn_mfma_f32_16x16x32_bf16(a1_, b0_, acc[1][0], 0, 0, 0); \
    acc[1][1] = __builtin_amdgcn_mfma_f32_16x16x32_bf16(a1_, b1_, acc[1][1], 0, 0, 0); \
  } \
} while (0)

  ISSUE(0, 0);
  for (int kt = 0; kt < NK; ++kt) {
    __syncthreads();                      // drains vmcnt: tile kt data landed;
                                          // all waves done reading buf[(kt+1)&1]
    if (kt + 1 < NK) ISSUE(kt + 1, (kt + 1) & 1);
    COMPUTE(kt & 1);
  }

  // epilogue: scale, bias, exact GELU
  const int ng = n0 + l16;
#pragma unroll
  for (int ni = 0; ni < 2; ++ni) {
    const int ngc = ng + ni * 16;
    const float s  = scale[ngc];
    const float bb = bias[ngc];
#pragma unroll
    for (int mi = 0; mi < 2; ++mi) {
#pragma unroll
      for (int j = 0; j < 4; ++j) {
        int m = w * 32 + mi * 16 + lq * 4 + j;
        float y = acc[mi][ni][j] * s + bb;
        float g = 0.5f * y * (1.0f + erff(y * 0.70710678118654752f));
        out[(size_t)m * N_DIM + ngc] = g;
      }
    }
  }
#undef ISSUE
#undef COMPUTE
}

extern "C" void kernel_launch(void* const* d_in, const int* in_sizes, int n_in,
                              void* d_out, int out_size, void* d_ws, size_t ws_size,
                              hipStream_t stream) {
  const float* x     = (const float*)d_in[0];
  const int*   wq    = (const int*)d_in[1];
  const float* scale = (const float*)d_in[2];
  const float* bias  = (const float*)d_in[3];
  float* out = (float*)d_out;

  const size_t xb_bytes = (size_t)M_DIM * K_DIM * sizeof(ushort_t);  // 1 MB
  if (ws_size >= xb_bytes) {
    ushort_t* xb = (ushort_t*)d_ws;
    convert_x_kernel<<<(M_DIM * K_DIM) / (256 * 4), 256, 0, stream>>>(x, xb);
    fp4gemm_kernel<true><<<NBLK, NT, 0, stream>>>(xb, wq, scale, bias, out);
  } else {
    fp4gemm_kernel<false><<<NBLK, NT, 0, stream>>>(x, wq, scale, bias, out);
  }
}

// Round 4
// 58.934 us; speedup vs baseline: 2.3201x; 1.1329x over previous
//
#include <hip/hip_runtime.h>
#include <stdint.h>

// FusedFP4Linear: out = gelu(x @ dequant(w_fp4)^T + bias)
// M=128, K=4096, N=16384. Weights [N, K/2] int32, low byte = two FP4 nibbles
// (hi nibble = even k, lo nibble = odd k).
// R4: counted-vmcnt pipeline (T3/T4): 4 LDS buffers, prefetch depth 2,
// raw s_barrier + s_waitcnt vmcnt(10) (never drain to 0 in main loop).
// Keeps R3's verified swizzled global_load_lds staging + v_perm FP4 decode.

#define M_DIM 128
#define K_DIM 4096
#define N_DIM 16384
#define KP    (K_DIM/2)        // 2048 ints per weight row
#define BN    32
#define BK    64
#define NK    (K_DIM/BK)       // 64 k-tiles
#define NT    256              // 4 waves
#define NBLK  (N_DIM/BN)       // 512 blocks

#define A_BYTES (M_DIM*BK*2)   // 16384 (128 rows x 128B)
#define B_BYTES (BN*(BK/2)*4)  // 4096  (32 rows x 128B packed)
#define NBUF    4
#define AOFF(b) ((b)*A_BYTES)
#define BOFF(b) (NBUF*A_BYTES + (b)*B_BYTES)
#define LDS_SZ  (NBUF*(A_BYTES + B_BYTES))   // 81920 -> 2 blocks/CU = 160KB

typedef __attribute__((ext_vector_type(8))) __bf16 bf16x8;
typedef __attribute__((ext_vector_type(4))) float  f32x4;
typedef unsigned short ushort_t;

__device__ __forceinline__ unsigned f2b_bits(float f) {
  unsigned u = __builtin_bit_cast(unsigned, f);
  u += 0x7FFFu + ((u >> 16) & 1u);   // RNE
  return u >> 16;
}

__global__ void convert_x_kernel(const float* __restrict__ x,
                                 ushort_t* __restrict__ xb) {
  int i = (blockIdx.x * blockDim.x + threadIdx.x) * 4;
  float4 v = *(const float4*)(x + i);
  ushort4 p;
  p.x = (ushort_t)f2b_bits(v.x);
  p.y = (ushort_t)f2b_bits(v.y);
  p.z = (ushort_t)f2b_bits(v.z);
  p.w = (ushort_t)f2b_bits(v.w);
  *(ushort4*)(xb + i) = p;
}

__device__ __forceinline__ void gl16(const void* g, void* l) {
  __builtin_amdgcn_global_load_lds(
      (const __attribute__((address_space(1))) void*)g,
      (__attribute__((address_space(3))) void*)l, 16, 0, 0);
}

// 4 packed ints (low bytes only) -> 8 bf16 (k-order: byte0.hi, byte0.lo, ...)
__device__ __forceinline__ bf16x8 decode8(uint4 p) {
  unsigned u01 = __builtin_amdgcn_perm(p.y, p.x, 0x04000400u);  // [x0,y0,x0,y0]
  unsigned u23 = __builtin_amdgcn_perm(p.w, p.z, 0x04000400u);  // [z0,w0,z0,w0]
  unsigned q   = __builtin_amdgcn_perm(u23, u01, 0x05040100u);  // [x0,y0,z0,w0]
  unsigned e  = (q >> 4) & 0x0F0F0F0Fu;    // even-k nibbles
  unsigned o  = q & 0x0F0F0F0Fu;           // odd-k nibbles
  unsigned em = e & 0x07070707u, om = o & 0x07070707u;
  unsigned elo = __builtin_amdgcn_perm(0xC0804000u, 0xC0800000u, em);
  unsigned ehi = __builtin_amdgcn_perm(0x40404040u, 0x3F3F3F00u, em);
  unsigned olo = __builtin_amdgcn_perm(0xC0804000u, 0xC0800000u, om);
  unsigned ohi = __builtin_amdgcn_perm(0x40404040u, 0x3F3F3F00u, om);
  ehi |= (e & 0x08080808u) << 4;           // sign -> bit7 of high byte
  ohi |= (o & 0x08080808u) << 4;
  unsigned t0 = __builtin_amdgcn_perm(ehi, elo, 0x05010400u);
  unsigned t1 = __builtin_amdgcn_perm(ohi, olo, 0x05010400u);
  unsigned t2 = __builtin_amdgcn_perm(ehi, elo, 0x07030602u);
  unsigned t3 = __builtin_amdgcn_perm(ohi, olo, 0x07030602u);
  uint4 r;
  r.x = __builtin_amdgcn_perm(t1, t0, 0x05040100u);  // bf16(k0)|bf16(k1)<<16
  r.y = __builtin_amdgcn_perm(t1, t0, 0x07060302u);
  r.z = __builtin_amdgcn_perm(t3, t2, 0x05040100u);
  r.w = __builtin_amdgcn_perm(t3, t2, 0x07060302u);
  return __builtin_bit_cast(bf16x8, r);
}

template<bool USE_XB>
__global__ __launch_bounds__(NT) void fp4gemm_kernel(
    const void* __restrict__ xsrc,        // bf16 xb (ws) or fp32 x
    const int*  __restrict__ wq,          // [N, KP]
    const float* __restrict__ scale,      // [N]
    const float* __restrict__ bias,       // [N]
    float* __restrict__ out) {            // [M, N]
  __shared__ __align__(16) uint8_t lds[LDS_SZ];

  const int t   = threadIdx.x;
  const int w   = t >> 6;                 // wave 0..3 (also m-quad)
  const int l   = t & 63;
  const int l16 = l & 15;
  const int lq  = l >> 4;

  // XCD-aware bijective swizzle (512 % 8 == 0)
  const int bid = blockIdx.x;
  const int n0  = ((bid & 7) * (NBLK / 8) + (bid >> 3)) * BN;

  // staging geometry: per global_load_lds inst, 256 thr x 16B = 4KB = 32 rows
  const int srow = w * 8 + (l >> 3);      // 0..31
  const int scb  = (l & 7) * 16;          // dest byte col (linear)
  const int scbs = scb ^ ((srow & 7) << 4);  // swizzled SOURCE byte col

  const uint8_t* xb  = (const uint8_t*)xsrc;  // bf16 rows: 8192 B
  const uint8_t* wqb = (const uint8_t*)wq;    // int rows: 8192 B

  // 5 gl16 per tile: 4 A + 1 B  (vmcnt += 5 per ISSUE)
#define ISSUE(kt_, buf_) do { \
  _Pragma("unroll") \
  for (int i_ = 0; i_ < 4; ++i_) \
    gl16(xb + (size_t)(i_ * 32 + srow) * 8192 + (size_t)(kt_) * 128 + scbs, \
         lds + AOFF(buf_) + i_ * 4096 + w * 1024); \
  gl16(wqb + (size_t)(n0 + srow) * 8192 + (size_t)(kt_) * 128 + scbs, \
       lds + BOFF(buf_) + w * 1024); \
} while (0)

  f32x4 acc[2][2] = {{f32x4{0,0,0,0}, f32x4{0,0,0,0}},
                     {f32x4{0,0,0,0}, f32x4{0,0,0,0}}};

  const int x7   = (l16 & 7) << 4;        // read-side swizzle (row&7 == l16&7)
  const int off0 = (lq << 4) ^ x7;
  const int ab0  = (w * 32 + l16) * 128;  // A row base (mi=0); mi=1 -> +2048
  const int bb0  = l16 * 128;             // B row base (ni=0); ni=1 -> +2048

#define COMPUTE(buf_) do { \
  const uint8_t* Ab_ = lds + AOFF(buf_); \
  const uint8_t* Bb_ = lds + BOFF(buf_); \
  _Pragma("unroll") \
  for (int ks_ = 0; ks_ < BK / 32; ++ks_) { \
    const int offk_ = off0 ^ (ks_ << 6); \
    bf16x8 a0_ = *(const bf16x8*)(Ab_ + ab0 + offk_); \
    bf16x8 a1_ = *(const bf16x8*)(Ab_ + ab0 + 2048 + offk_); \
    uint4 pb0_ = *(const uint4*)(Bb_ + bb0 + offk_); \
    uint4 pb1_ = *(const uint4*)(Bb_ + bb0 + 2048 + offk_); \
    bf16x8 b0_ = decode8(pb0_); \
    bf16x8 b1_ = decode8(pb1_); \
    acc[0][0] = __builtin_amdgcn_mfma_f32_16x16x32_bf16(a0_, b0_, acc[0][0], 0, 0, 0); \
    acc[0][1] = __builtin_amdgcn_mfma_f32_16x16x32_bf16(a0_, b1_, acc[0][1], 0, 0, 0); \
    acc[1][0] = __builtin_amdgcn_mfma_f32_16x16x32_bf16(a1_, b0_, acc[1][0], 0, 0, 0); \
    acc[1][1] = __builtin_amdgcn_mfma_f32_16x16x32_bf16(a1_, b1_, acc[1][1], 0, 0, 0); \
  } \
} while (0)

  if constexpr (USE_XB) {
    // ---- counted-vmcnt pipeline, depth 2, 4 buffers, 1 barrier/tile ----
    ISSUE(0, 0);
    ISSUE(1, 1);
    for (int kt = 0; kt < NK - 2; ++kt) {
      ISSUE(kt + 2, (kt + 2) & (NBUF - 1));
      asm volatile("s_waitcnt vmcnt(10)" ::: "memory");  // tile kt landed
      __builtin_amdgcn_s_barrier();
      __builtin_amdgcn_sched_barrier(0);
      COMPUTE(kt & (NBUF - 1));
    }
    asm volatile("s_waitcnt vmcnt(5)" ::: "memory");     // tile NK-2 landed
    __builtin_amdgcn_s_barrier();
    __builtin_amdgcn_sched_barrier(0);
    COMPUTE((NK - 2) & (NBUF - 1));
    asm volatile("s_waitcnt vmcnt(0)" ::: "memory");     // tile NK-1 landed
    __builtin_amdgcn_s_barrier();
    __builtin_amdgcn_sched_barrier(0);
    COMPUTE((NK - 1) & (NBUF - 1));
  } else {
    // fallback (ws too small): simple double-buffer, reg-staged fp32->bf16
#define ISSUE_F(kt_, buf_) do { \
    _Pragma("unroll") \
    for (int i_ = 0; i_ < 4; ++i_) { \
      const float* xf_ = (const float*)xsrc + \
          (size_t)(i_ * 32 + srow) * K_DIM + (size_t)(kt_) * BK + (scb >> 1); \
      float4 v0_ = *(const float4*)(xf_); \
      float4 v1_ = *(const float4*)(xf_ + 4); \
      uint4 pk_ = make_uint4(f2b_bits(v0_.x) | (f2b_bits(v0_.y) << 16), \
                             f2b_bits(v0_.z) | (f2b_bits(v0_.w) << 16), \
                             f2b_bits(v1_.x) | (f2b_bits(v1_.y) << 16), \
                             f2b_bits(v1_.z) | (f2b_bits(v1_.w) << 16)); \
      *(uint4*)(lds + AOFF(buf_) + (size_t)(i_ * 32 + srow) * 128 + \
                (scb ^ ((srow & 7) << 4))) = pk_; \
    } \
    gl16(wqb + (size_t)(n0 + srow) * 8192 + (size_t)(kt_) * 128 + scbs, \
         lds + BOFF(buf_) + w * 1024); \
} while (0)
    for (int kt = 0; kt < NK; ++kt) {
      __syncthreads();
      ISSUE_F(kt, kt & 1);
      __syncthreads();
      COMPUTE(kt & 1);
    }
#undef ISSUE_F
  }

  // epilogue: scale, bias, exact GELU
  const int ng = n0 + l16;
#pragma unroll
  for (int ni = 0; ni < 2; ++ni) {
    const int ngc = ng + ni * 16;
    const float s  = scale[ngc];
    const float bb = bias[ngc];
#pragma unroll
    for (int mi = 0; mi < 2; ++mi) {
#pragma unroll
      for (int j = 0; j < 4; ++j) {
        int m = w * 32 + mi * 16 + lq * 4 + j;
        float y = acc[mi][ni][j] * s + bb;
        float g = 0.5f * y * (1.0f + erff(y * 0.70710678118654752f));
        out[(size_t)m * N_DIM + ngc] = g;
      }
    }
  }
#undef ISSUE
#undef COMPUTE
}

extern "C" void kernel_launch(void* const* d_in, const int* in_sizes, int n_in,
                              void* d_out, int out_size, void* d_ws, size_t ws_size,
                              hipStream_t stream) {
  const float* x     = (const float*)d_in[0];
  const int*   wq    = (const int*)d_in[1];
  const float* scale = (const float*)d_in[2];
  const float* bias  = (const float*)d_in[3];
  float* out = (float*)d_out;

  const size_t xb_bytes = (size_t)M_DIM * K_DIM * sizeof(ushort_t);  // 1 MB
  if (ws_size >= xb_bytes) {
    ushort_t* xb = (ushort_t*)d_ws;
    convert_x_kernel<<<(M_DIM * K_DIM) / (256 * 4), 256, 0, stream>>>(x, xb);
    fp4gemm_kernel<true><<<NBLK, NT, 0, stream>>>(xb, wq, scale, bias, out);
  } else {
    fp4gemm_kernel<false><<<NBLK, NT, 0, stream>>>(x, wq, scale, bias, out);
  }
}

// Round 5
// 42.140 us; speedup vs baseline: 3.2446x; 1.3985x over previous
//
#include <hip/hip_runtime.h>
#include <stdint.h>

// FusedFP4Linear: out = gelu(x @ dequant(w_fp4)^T + bias)
// M=128, K=4096, N=16384. Weights [N, K/2] int32, low byte = two FP4 nibbles
// (hi nibble = even k, lo nibble = odd k).
// R5: BN=64 / grid=256 / 8 waves (4m x 2n). A staged via global_load_lds
// (depth 2, pre-swizzled source). B staged global->reg->v_perm-decode->LDS
// (decode ONCE per block, depth ~3-4 in 4 reg slots). NBUF=4 (96KB LDS),
// counted vmcnt with hand-derived waits, peeled prologue/tail.

#define M_DIM 128
#define K_DIM 4096
#define N_DIM 16384
#define BN    64
#define BK    64
#define NK    (K_DIM/BK)       // 64
#define NT    512              // 8 waves
#define NBLK  (N_DIM/BN)       // 256

#define A_BYTES 16384          // 128 rows x 128B bf16
#define B_BYTES 8192           // 64 rows x 128B bf16 (decoded)
#define NBUF    4
#define AOFF(b) ((b)*A_BYTES)
#define BOFF(b) (NBUF*A_BYTES + (b)*B_BYTES)
#define LDS_SZ  (NBUF*(A_BYTES+B_BYTES))   // 98304

typedef __attribute__((ext_vector_type(8))) __bf16 bf16x8;
typedef __attribute__((ext_vector_type(4))) float  f32x4;
typedef unsigned short ushort_t;

__device__ __forceinline__ unsigned f2b_bits(float f) {
  unsigned u = __builtin_bit_cast(unsigned, f);
  u += 0x7FFFu + ((u >> 16) & 1u);   // RNE
  return u >> 16;
}

__global__ void convert_x_kernel(const float* __restrict__ x,
                                 ushort_t* __restrict__ xb) {
  int i = (blockIdx.x * blockDim.x + threadIdx.x) * 4;
  float4 v = *(const float4*)(x + i);
  ushort4 p;
  p.x = (ushort_t)f2b_bits(v.x);
  p.y = (ushort_t)f2b_bits(v.y);
  p.z = (ushort_t)f2b_bits(v.z);
  p.w = (ushort_t)f2b_bits(v.w);
  *(ushort4*)(xb + i) = p;
}

__device__ __forceinline__ void gl16(const void* g, void* l) {
  __builtin_amdgcn_global_load_lds(
      (const __attribute__((address_space(1))) void*)g,
      (__attribute__((address_space(3))) void*)l, 16, 0, 0);
}

// 4 packed ints (low bytes only) -> 8 bf16 (k-order: byte0.hi, byte0.lo, ...)
__device__ __forceinline__ bf16x8 decode8(uint4 p) {
  unsigned u01 = __builtin_amdgcn_perm(p.y, p.x, 0x04000400u);
  unsigned u23 = __builtin_amdgcn_perm(p.w, p.z, 0x04000400u);
  unsigned q   = __builtin_amdgcn_perm(u23, u01, 0x05040100u);  // [x0,y0,z0,w0]
  unsigned e  = (q >> 4) & 0x0F0F0F0Fu;    // even-k nibbles
  unsigned o  = q & 0x0F0F0F0Fu;           // odd-k nibbles
  unsigned em = e & 0x07070707u, om = o & 0x07070707u;
  unsigned elo = __builtin_amdgcn_perm(0xC0804000u, 0xC0800000u, em);
  unsigned ehi = __builtin_amdgcn_perm(0x40404040u, 0x3F3F3F00u, em);
  unsigned olo = __builtin_amdgcn_perm(0xC0804000u, 0xC0800000u, om);
  unsigned ohi = __builtin_amdgcn_perm(0x40404040u, 0x3F3F3F00u, om);
  ehi |= (e & 0x08080808u) << 4;           // sign -> bit7 of high byte
  ohi |= (o & 0x08080808u) << 4;
  unsigned t0 = __builtin_amdgcn_perm(ehi, elo, 0x05010400u);
  unsigned t1 = __builtin_amdgcn_perm(ohi, olo, 0x05010400u);
  unsigned t2 = __builtin_amdgcn_perm(ehi, elo, 0x07030602u);
  unsigned t3 = __builtin_amdgcn_perm(ohi, olo, 0x07030602u);
  uint4 r;
  r.x = __builtin_amdgcn_perm(t1, t0, 0x05040100u);
  r.y = __builtin_amdgcn_perm(t1, t0, 0x07060302u);
  r.z = __builtin_amdgcn_perm(t3, t2, 0x05040100u);
  r.w = __builtin_amdgcn_perm(t3, t2, 0x07060302u);
  return __builtin_bit_cast(bf16x8, r);
}

#define MFMA16(a_, b_, c_) __builtin_amdgcn_mfma_f32_16x16x32_bf16(a_, b_, c_, 0, 0, 0)

template<bool USE_XB>
__global__ __launch_bounds__(NT) void fp4gemm_kernel(
    const void* __restrict__ xsrc,        // bf16 xb (ws) or fp32 x
    const int*  __restrict__ wq,          // [N, K/2] packed
    const float* __restrict__ scale,      // [N]
    const float* __restrict__ bias,       // [N]
    float* __restrict__ out) {            // [M, N]
  __shared__ __align__(16) uint8_t lds[LDS_SZ];

  const int t   = threadIdx.x;
  const int w   = t >> 6;                 // wave 0..7
  const int l   = t & 63;
  const int l16 = l & 15;
  const int lq  = l >> 4;
  const int mq  = w >> 1;                 // 0..3: rows mq*32..+31
  const int nh  = w & 1;                  // 0..1: cols nh*32..+31

  // XCD-aware bijective swizzle (256 % 8 == 0)
  const int bid = blockIdx.x;
  const int n0  = ((bid & 7) * (NBLK / 8) + (bid >> 3)) * BN;

  // staging geometry: 512 threads x 16B = 8KB = 64 rows x 128B
  const int srow = t >> 3;                // 0..63
  const int scol = (t & 7) * 16;          // byte col 0..112
  const int sswz = (srow & 7) << 4;
  const int scbs = scol ^ sswz;           // swizzled A-source col (gl16: swz on src)
  const int bwr  = srow * 128 + (scol ^ sswz);  // B LDS write offset (swz on write)

  const uint8_t* xb  = (const uint8_t*)xsrc;  // bf16 row = 8192 B
  const uint8_t* wqb = (const uint8_t*)wq;    // int row = 8192 B

  uint4 rs0, rs1, rs2, rs3;               // B packed reg slots (slot = kt & 3)

#define ISSUE_A(k_, b_) do { \
  gl16(xb + (size_t)(srow) * 8192 + (size_t)(k_) * 128 + scbs, \
       lds + AOFF(b_) + w * 1024); \
  gl16(xb + (size_t)(64 + srow) * 8192 + (size_t)(k_) * 128 + scbs, \
       lds + AOFF(b_) + 8192 + w * 1024); \
} while (0)

#define ISSUE_B(k_, s_) do { \
  rs##s_ = *(const uint4*)(wqb + (size_t)(n0 + srow) * 8192 + (size_t)(k_) * 128 + scol); \
} while (0)

#define DECODE_B(s_, b_) do { \
  *(bf16x8*)(lds + BOFF(b_) + bwr) = decode8(rs##s_); \
} while (0)

#define WAITV(N_) asm volatile("s_waitcnt vmcnt(" #N_ ")" ::: "memory")
#define BARRIER() do { \
  asm volatile("s_waitcnt lgkmcnt(0)" ::: "memory"); \
  __builtin_amdgcn_s_barrier(); \
  __builtin_amdgcn_sched_barrier(0); \
} while (0)

  f32x4 acc00 = {0,0,0,0}, acc01 = {0,0,0,0};
  f32x4 acc10 = {0,0,0,0}, acc11 = {0,0,0,0};

  const int cBase = (lq << 4) ^ ((l16 & 7) << 4);
  const int aR0 = (mq * 32 + l16) * 128;       // +2048 for mi=1
  const int bR0 = (nh * 32 + l16) * 128;       // +2048 for ni=1

#define COMPUTE(b_) do { \
  const uint8_t* Ab_ = lds + AOFF(b_); \
  const uint8_t* Bb_ = lds + BOFF(b_); \
  _Pragma("unroll") \
  for (int ks_ = 0; ks_ < 2; ++ks_) { \
    const int cS_ = (ks_ << 6) ^ cBase; \
    bf16x8 a0_ = *(const bf16x8*)(Ab_ + aR0 + cS_); \
    bf16x8 a1_ = *(const bf16x8*)(Ab_ + aR0 + 2048 + cS_); \
    bf16x8 b0_ = *(const bf16x8*)(Bb_ + bR0 + cS_); \
    bf16x8 b1_ = *(const bf16x8*)(Bb_ + bR0 + 2048 + cS_); \
    acc00 = MFMA16(a0_, b0_, acc00); \
    acc01 = MFMA16(a0_, b1_, acc01); \
    acc10 = MFMA16(a1_, b0_, acc10); \
    acc11 = MFMA16(a1_, b1_, acc11); \
  } \
} while (0)

// main-loop body: iter k_ (slot/buf params are compile-time constants)
//   u_  = (k_+2)&3  (A dest buf, B decode slot+buf, B issue slot)
//   cb_ = (k_)&3    (compute buf)
#define BODY(k_, u_, cb_) do { \
  ISSUE_A((k_) + 2, u_); \
  WAITV(6); \
  BARRIER(); \
  DECODE_B(u_, u_); \
  ISSUE_B((k_) + 6, u_); \
  COMPUTE(cb_); \
} while (0)

  if constexpr (USE_XB) {
    // ---- prologue ----
    ISSUE_B(0, 0); ISSUE_B(1, 1); ISSUE_B(2, 2); ISSUE_B(3, 3);
    ISSUE_A(0, 0); ISSUE_A(1, 1);
    WAITV(4);                       // B0..B3 arrived
    DECODE_B(0, 0); DECODE_B(1, 1);
    ISSUE_B(4, 0); ISSUE_B(5, 1);
    // kt = 0
    ISSUE_A(2, 2); WAITV(6); BARRIER();
    DECODE_B(2, 2); ISSUE_B(6, 2); COMPUTE(0);
    // kt = 1
    ISSUE_A(3, 3); WAITV(7); BARRIER();
    DECODE_B(3, 3); ISSUE_B(7, 3); COMPUTE(1);
    // ---- main loop: kt = 2..57 (56 iters) ----
    for (int j = 0; j < 14; ++j) {
      const int kt = 2 + 4 * j;
      BODY(kt + 0, 0, 2);
      BODY(kt + 1, 1, 3);
      BODY(kt + 2, 2, 0);
      BODY(kt + 3, 3, 1);
    }
    // ---- tail ----
    ISSUE_A(60, 0); WAITV(6); BARRIER(); DECODE_B(0, 0); COMPUTE(2);  // kt=58
    ISSUE_A(61, 1); WAITV(5); BARRIER(); DECODE_B(1, 1); COMPUTE(3);  // kt=59
    ISSUE_A(62, 2); WAITV(4); BARRIER(); DECODE_B(2, 2); COMPUTE(0);  // kt=60
    ISSUE_A(63, 3); WAITV(4); BARRIER(); DECODE_B(3, 3); COMPUTE(1);  // kt=61
    WAITV(2); BARRIER(); COMPUTE(2);                                   // kt=62
    WAITV(0); BARRIER(); COMPUTE(3);                                   // kt=63
  } else {
    // fallback (ws too small): simple 2-buffer __syncthreads pipeline
    for (int kt = 0; kt < NK; ++kt) {
      __syncthreads();
#pragma unroll
      for (int i = 0; i < 2; ++i) {
        const float* xf = (const float*)xsrc +
            (size_t)(i * 64 + srow) * K_DIM + (size_t)kt * BK + (scol >> 1);
        float4 v0 = *(const float4*)(xf);
        float4 v1 = *(const float4*)(xf + 4);
        uint4 pk = make_uint4(f2b_bits(v0.x) | (f2b_bits(v0.y) << 16),
                              f2b_bits(v0.z) | (f2b_bits(v0.w) << 16),
                              f2b_bits(v1.x) | (f2b_bits(v1.y) << 16),
                              f2b_bits(v1.z) | (f2b_bits(v1.w) << 16));
        *(uint4*)(lds + AOFF(kt & 1) + (size_t)(i * 64 + srow) * 128 +
                  (scol ^ sswz)) = pk;
      }
      {
        uint4 pv = *(const uint4*)(wqb + (size_t)(n0 + srow) * 8192 +
                                   (size_t)kt * 128 + scol);
        *(bf16x8*)(lds + BOFF(kt & 1) + bwr) = decode8(pv);
      }
      __syncthreads();
      COMPUTE(kt & 1);
    }
  }

  // ---- epilogue: scale, bias, exact GELU ----
  const int ng = n0 + nh * 32 + l16;
#pragma unroll
  for (int ni = 0; ni < 2; ++ni) {
    const int ngc = ng + ni * 16;
    const float s  = scale[ngc];
    const float bb = bias[ngc];
    f32x4 v0 = ni ? acc01 : acc00;
    f32x4 v1 = ni ? acc11 : acc10;
#pragma unroll
    for (int mi = 0; mi < 2; ++mi) {
      f32x4 vv = mi ? v1 : v0;
#pragma unroll
      for (int j = 0; j < 4; ++j) {
        int m = mq * 32 + mi * 16 + lq * 4 + j;
        float y = vv[j] * s + bb;
        float g = 0.5f * y * (1.0f + erff(y * 0.70710678118654752f));
        out[(size_t)m * N_DIM + ngc] = g;
      }
    }
  }
#undef ISSUE_A
#undef ISSUE_B
#undef DECODE_B
#undef WAITV
#undef BARRIER
#undef COMPUTE
#undef BODY
}

extern "C" void kernel_launch(void* const* d_in, const int* in_sizes, int n_in,
                              void* d_out, int out_size, void* d_ws, size_t ws_size,
                              hipStream_t stream) {
  const float* x     = (const float*)d_in[0];
  const int*   wq    = (const int*)d_in[1];
  const float* scale = (const float*)d_in[2];
  const float* bias  = (const float*)d_in[3];
  float* out = (float*)d_out;

  const size_t xb_bytes = (size_t)M_DIM * K_DIM * sizeof(ushort_t);  // 1 MB
  if (ws_size >= xb_bytes) {
    ushort_t* xb = (ushort_t*)d_ws;
    convert_x_kernel<<<(M_DIM * K_DIM) / (256 * 4), 256, 0, stream>>>(x, xb);
    fp4gemm_kernel<true><<<NBLK, NT, 0, stream>>>(xb, wq, scale, bias, out);
  } else {
    fp4gemm_kernel<false><<<NBLK, NT, 0, stream>>>(x, wq, scale, bias, out);
  }
}